// Round 25
// baseline (101.962 us; speedup 1.0000x reference)
//
#include <hip/hip_runtime.h>
#include <hip/hip_bf16.h>

using u16 = unsigned short;
using u32 = unsigned int;
using short8 = __attribute__((ext_vector_type(8))) short;  // 8 bf16
using f32x4  = __attribute__((ext_vector_type(4))) float;
using u32x4  = __attribute__((ext_vector_type(4))) u32;
using u32x2  = __attribute__((ext_vector_type(2))) u32;

union V16 { u32x4 u; short8 s; };

__device__ __forceinline__ u16 f2b(float f) {
  u32 u = __float_as_uint(f);
  u32 r = (u + 0x7FFFu + ((u >> 16) & 1u)) >> 16;
  return (u16)r;
}
__device__ __forceinline__ u32 pk2(u16 a, u16 b) {
  return (u32)a | ((u32)b << 16);
}
// packed f32->bf16 pair (RNE), single VOP3 instr (no builtin on gfx950)
__device__ __forceinline__ u32 cvtpk(float lo, float hi) {
  u32 r;
  asm("v_cvt_pk_bf16_f32 %0, %1, %2" : "=v"(r) : "v"(lo), "v"(hi));
  return r;
}
// raw 2^x (v_exp_f32 computes exp2 natively)
__device__ __forceinline__ float ex2(float x) {
  float r;
  asm("v_exp_f32 %0, %1" : "=v"(r) : "v"(x));
  return r;
}
// async global->LDS, 16B per lane; dest = wave-uniform base + lane*16 (linear)
__device__ __forceinline__ void gld16(const u16* g, u16* l) {
  __builtin_amdgcn_global_load_lds(
      (const __attribute__((address_space(1))) u32*)g,
      (__attribute__((address_space(3))) u32*)l, 16, 0, 0);
}

#define KSCALE 0.18033688011f  // 0.125 * log2(e): folds attn scale into exp2 domain
#define SMAX   12.0f           // static softmax shift (folded into cbias)

// Fragment-image layout (shared by all GEMM operands):
//   img[(tile128*16 + ks)*16 + c][l][e],  c=chunk 0..15, l=lane 0..63, e=0..7
//   c = o*8 + f*2 + kk:  row(tile-local) = o*64 + f*16 + (l&15)
//                        col(k)          = ks*64 + kk*32 + (l>>4)*8 + e

// ---------------------------------------------------------------------------
// Kernel 1b: maskscan — per-batch compaction.  Grid (16 heads, 2 batch).
// h==0 writes inv (compact->orig map), cbias, ntb[b]=ntiles, ntb[2+b]=nvalid.
// Every block zeroes its head's K/V image pad slots (keys nvalid..pad64).
// ---------------------------------------------------------------------------
__global__ __launch_bounds__(256) void maskscan(
    const int* __restrict__ mask, int* __restrict__ inv,
    float* __restrict__ cbias, int* __restrict__ ntb,
    u16* __restrict__ Kimg, u16* __restrict__ Vimg)
{
  const int h = blockIdx.x, b = blockIdx.y;
  const int tid = threadIdx.x;
  __shared__ int ssum[256];

  int m8[8], s = 0;
#pragma unroll
  for (int i = 0; i < 8; ++i) {
    m8[i] = mask[b * 2048 + tid * 8 + i] ? 1 : 0;
    s += m8[i];
  }
  ssum[tid] = s;
  __syncthreads();
  for (int off = 1; off < 256; off <<= 1) {
    int v = (tid >= off) ? ssum[tid - off] : 0;
    __syncthreads();
    ssum[tid] += v;
    __syncthreads();
  }
  const int nvalid = ssum[255];
  int run = ssum[tid] - s;  // exclusive prefix

  if (h == 0) {
    int run2 = run;
#pragma unroll
    for (int i = 0; i < 8; ++i) {
      if (m8[i]) { inv[b * 2048 + run2] = tid * 8 + i; ++run2; }
    }
#pragma unroll
    for (int i = 0; i < 8; ++i) {
      const int idx = tid * 8 + i;
      cbias[b * 2048 + idx] = (idx < nvalid) ? -SMAX : -1e30f;
    }
    if (tid == 0) { ntb[b] = (nvalid + 63) >> 6; ntb[2 + b] = nvalid; }
  }

  // zero K/V pad slots for this head (keys nvalid .. pad64-1)
  const int pend = ((nvalid + 63) >> 6) << 6;
  for (int p = nvalid + tid; p < pend; p += 256) {
    const int kt2 = p >> 6, r = p & 63;
    const size_t base = ((size_t)((b * 16 + h) * 32 + kt2)) * 4096;
    const int t2 = ((r >> 5) << 1) | ((r >> 2) & 1);
    const int ll2 = (((r >> 3) & 3) << 2) | (r & 3);
#pragma unroll
    for (int s2 = 0; s2 < 2; ++s2)
#pragma unroll
      for (int lgk = 0; lgk < 4; ++lgk)
#pragma unroll
        for (int e = 0; e < 8; ++e)
          Kimg[base + (t2 * 2 + s2) * 512 + (lgk * 16 + ll2) * 8 + e] = 0;
    const int sv = r >> 5, lgv = (r >> 3) & 3, e0 = r & 7;
#pragma unroll
    for (int td = 0; td < 4; ++td)
#pragma unroll
      for (int llv = 0; llv < 16; ++llv)
        Vimg[base + (sv * 4 + td) * 512 + (lgv * 16 + llv) * 8 + e0] = 0;
  }
}

// ---------------------------------------------------------------------------
// Kernel 1: FUSED weight + activation fragment-image conversion.
// Grid (16, 32, 7), 256 threads.
//   z = 0..3: weight images (Wq,Wk,Wv -> Wt slices; Wo -> WoT).  Only blocks
//             with bx<8 && (by&1)==0 are active (128 per slice); nt=bx,
//             ks=by>>1 reproduces the original wconv exactly.
//   z = 4..6: activation images (qry,key,val -> Af slices).  z>=5 gather
//             compacted rows through inv (depends on maskscan, launched prior).
// Fusing puts the small weight-conversion work inside the big dispatch's
// occupancy instead of a separate half-idle launch.
// ---------------------------------------------------------------------------
__global__ __launch_bounds__(256) void convfuse(
    const float* __restrict__ Wq, const float* __restrict__ Wk,
    const float* __restrict__ Wv, const float* __restrict__ Wo,
    u16* __restrict__ Wt, u16* __restrict__ WoT,
    const float* __restrict__ Aq, const float* __restrict__ Ak,
    const float* __restrict__ Av, u16* __restrict__ Af,
    const int* __restrict__ inv, const int* __restrict__ ntbv,
    size_t zstride)
{
  const int z = blockIdx.z;
  const int tid = threadIdx.x;

  if (z < 4) {
    // ---- weight image (original wconv) ----
    if (blockIdx.x >= 8 || (blockIdx.y & 1)) return;
    const int nt = blockIdx.x, ks = blockIdx.y >> 1;
    __shared__ u16 T[64][130];
    const float* src = (z == 0) ? Wq : (z == 1) ? Wk : (z == 2) ? Wv : Wo;
    u16* dst = (z < 3) ? (Wt + (size_t)z * 1048576) : WoT;

    {
      const int kl = tid >> 2, nl0 = (tid & 3) * 32;
      const float* sp = src + (size_t)(ks * 64 + kl) * 1024 + nt * 128 + nl0;
#pragma unroll
      for (int i = 0; i < 8; ++i) {
        f32x4 x = *(const f32x4*)(sp + i * 4);
        T[kl][nl0 + i * 4 + 0] = f2b(x[0]);
        T[kl][nl0 + i * 4 + 1] = f2b(x[1]);
        T[kl][nl0 + i * 4 + 2] = f2b(x[2]);
        T[kl][nl0 + i * 4 + 3] = f2b(x[3]);
      }
    }
    __syncthreads();

    const int c = tid >> 4, l0 = (tid & 15) * 4;
    u16* dp = dst + ((size_t)(nt * 16 + ks) * 16 + c) * 512 + l0 * 8;
#pragma unroll
    for (int dl = 0; dl < 4; ++dl) {
      const int l = l0 + dl;
      const int kl = (c & 1) * 32 + (l >> 4) * 8;
      const int nl = (c >> 3) * 64 + ((c >> 1) & 3) * 16 + (l & 15);
      u32x4 u;
#pragma unroll
      for (int p = 0; p < 4; ++p)
        u[p] = pk2(T[kl + 2 * p][nl], T[kl + 2 * p + 1][nl]);
      *(u32x4*)(dp + dl * 8) = u;
    }
  } else {
    // ---- activation image (original aconv) ----
    const int za = z - 4;
    const float* A = (za == 0) ? Aq : (za == 1) ? Ak : Av;
    u16* dst = Af + (size_t)za * zstride;
    const int ks = blockIdx.x, mt = blockIdx.y;
    const int r = tid >> 1, h = tid & 1;

    int srow = mt * 128 + r;
    if (za >= 1) {
      const int b = srow >> 11, cpos = srow & 2047;
      if (cpos >= ntbv[2 + b]) return;           // beyond valid keys: skip
      srow = b * 2048 + inv[b * 2048 + cpos];    // gather original row
    }

    const f32x4* sp = (const f32x4*)(A + (size_t)srow * 1024 + ks * 64 + h * 32);
    const int c = ((r >> 6) << 3) | (((r >> 4) & 3) << 1) | h;
    u16* dp = dst + ((size_t)(mt * 16 + ks) * 16 + c) * 512 + (r & 15) * 8;

#pragma unroll
    for (int lg = 0; lg < 4; ++lg) {
      f32x4 x0 = sp[2 * lg], x1 = sp[2 * lg + 1];
      u32x4 u;
      u[0] = cvtpk(x0[0], x0[1]); u[1] = cvtpk(x0[2], x0[3]);
      u[2] = cvtpk(x1[0], x1[1]); u[3] = cvtpk(x1[2], x1[3]);
      *(u32x4*)(dp + lg * 128) = u;
    }
  }
}

// ---------------------------------------------------------------------------
// Kernel 2: QKV projection GEMM.  BK=32, 3-buffer LDS (48KB -> 3 blocks/CU),
// ONE barrier per step, depth-2 prefetch with counted vmcnt(2).
// z-dependent XCD map; compacted K/V with early-exit and guarded epilogues.
// ---------------------------------------------------------------------------
__global__ __launch_bounds__(512, 4) void gemm_qkv_k(
    const u16* __restrict__ Af, const u16* __restrict__ Wt,
    u16* __restrict__ Qw, u16* __restrict__ Kw, u16* __restrict__ Vw,
    const int* __restrict__ ntbv, int z0, size_t azs)
{
  __shared__ u16 As[3][4096];   // 8 chunks x 512 (BK=32 A tile)
  __shared__ u16 Bs[3][4096];   // 8 chunks x 512 (BK=32 B tile)

  const int L = blockIdx.x;
  const int xcd = L & 7, idx = L >> 3;
  const int zi = idx >> 5;
  const int z = z0 + zi;
  const int mt = (z == 0) ? ((xcd << 2) | (idx & 3))     // Q: XCD-local A
                          : (((idx & 3) << 3) | xcd);    // K/V: spread valid mts
  const int nt = (idx >> 2) & 7;

  // compacted K/V: skip tiles entirely beyond this batch's valid rows
  if (z >= 1) {
    const int b0 = (mt * 128) >> 11;
    if ((mt * 128 & 2047) >= ntbv[2 + b0]) return;
  }

  const u16* Aimg = Af + (size_t)zi * azs;
  const u16* Bimg = Wt + (size_t)z * 1048576;
  u16* O = (z == 0) ? Qw : (z == 1) ? Kw : Vw;

  const int tid = threadIdx.x;
  const int w = tid >> 6, l = tid & 63, lg = l >> 4, ll = l & 15;
  const int wr = w >> 2, wc = w & 3;
  const size_t ab = (size_t)mt * 131072;
  const size_t bb = (size_t)nt * 131072;

  f32x4 acc[4][2];
#pragma unroll
  for (int i = 0; i < 4; ++i)
#pragma unroll
    for (int t = 0; t < 2; ++t)
      acc[i][t] = (f32x4){0.f, 0.f, 0.f, 0.f};

#define QKV_ISSUE(sx, bf) do {                                              \
    const int ksi_ = (sx) >> 1, kkx_ = (sx) & 1;                            \
    const size_t off_ = (size_t)ksi_ * 8192 +                               \
        (size_t)(((w >> 2) * 8) + ((w & 3) * 2) + kkx_) * 512 + l * 8;      \
    gld16(Aimg + ab + off_, &As[bf][w * 512]);                              \
    gld16(Bimg + bb + off_, &Bs[bf][w * 512]);                              \
  } while (0)

  QKV_ISSUE(0, 0);
  QKV_ISSUE(1, 1);

  for (int s = 0; s < 32; ++s) {
    const int cur = s % 3;
    if (s < 31) asm volatile("s_waitcnt vmcnt(2)" ::: "memory");  // own tile done
    else        asm volatile("s_waitcnt vmcnt(0)" ::: "memory");
    __builtin_amdgcn_sched_barrier(0);
    __builtin_amdgcn_s_barrier();   // publishes step-s; proves s-1 reads done
    __builtin_amdgcn_sched_barrier(0);

    if (s + 2 < 32) QKV_ISSUE(s + 2, (s + 2) % 3);

    short8 afr[4], bfr[2];
#pragma unroll
    for (int i = 0; i < 4; ++i) {
      V16 v; v.u = *(const u32x4*)&As[cur][(wr * 4 + i) * 512 + l * 8];
      afr[i] = v.s;
    }
#pragma unroll
    for (int t = 0; t < 2; ++t) {
      V16 v; v.u = *(const u32x4*)&Bs[cur][((wc >> 1) * 4 + (wc & 1) * 2 + t) * 512 + l * 8];
      bfr[t] = v.s;
    }
#pragma unroll
    for (int i = 0; i < 4; ++i)
#pragma unroll
      for (int t = 0; t < 2; ++t)
        acc[i][t] = __builtin_amdgcn_mfma_f32_16x16x32_bf16(afr[i], bfr[t], acc[i][t], 0, 0, 0);
  }
#undef QKV_ISSUE

  const int m0 = mt * 128, n0 = nt * 128;
  if (z == 0) {
#pragma unroll
    for (int i = 0; i < 4; ++i)
#pragma unroll
      for (int t = 0; t < 2; ++t) {
        const int n = n0 + wc * 32 + t * 16 + ll;
        const int h = n >> 6, dd = n & 63;
#pragma unroll
        for (int j = 0; j < 4; ++j) {
          const int m = m0 + wr * 64 + i * 16 + lg * 4 + j;
          const int bbk = m >> 11, pos = m & 2047;
          O[((size_t)(bbk * 16 + h) * 2048 + pos) * 64 + dd] = f2b(acc[i][t][j]);
        }
      }
  } else if (z == 1) {
    const int bbk = m0 >> 11;
    const int nv = ntbv[2 + bbk];
#pragma unroll
    for (int i = 0; i < 4; ++i)
#pragma unroll
      for (int t = 0; t < 2; ++t) {
        const int n = n0 + wc * 32 + t * 16 + ll;
        const int h = n >> 6, dd = n & 63;
        const int s = dd >> 5, lgk = (dd >> 3) & 3, e = dd & 7;
#pragma unroll
        for (int j = 0; j < 4; ++j) {
          const int m = m0 + wr * 64 + i * 16 + lg * 4 + j;
          const int cpos = m & 2047;
          if (cpos < nv) {
            const int kt2 = cpos >> 6, r = cpos & 63;
            const int t2 = ((r >> 5) << 1) | ((r >> 2) & 1);
            const int ll2 = (((r >> 3) & 3) << 2) | (r & 3);
            O[((size_t)((bbk * 16 + h) * 32 + kt2)) * 4096 + (t2 * 2 + s) * 512 + (lgk * 16 + ll2) * 8 + e]
                = f2b(acc[i][t][j] * KSCALE);
          }
        }
      }
  } else {
    const int bbk = m0 >> 11;
    const int nv = ntbv[2 + bbk];
#pragma unroll
    for (int i = 0; i < 4; ++i)
#pragma unroll
      for (int t = 0; t < 2; ++t) {
        const int n = n0 + wc * 32 + t * 16 + ll;
        const int h = n >> 6, dd = n & 63;
        const int td = dd >> 4, llv = dd & 15;
        const int mb0 = m0 + wr * 64 + i * 16 + lg * 4;   // j = 0
        const int cp0 = mb0 & 2047;
        const int kt2 = cp0 >> 6, kk = cp0 & 63;
        const int s = kk >> 5, lgv = (kk >> 3) & 3, e0 = kk & 7;
        u16* dstp = &O[((size_t)((bbk * 16 + h) * 32 + kt2)) * 4096 + (s * 4 + td) * 512 + (lgv * 16 + llv) * 8 + e0];
        if (cp0 + 3 < nv) {
          u32x2 wv;
          wv[0] = pk2(f2b(acc[i][t][0]), f2b(acc[i][t][1]));
          wv[1] = pk2(f2b(acc[i][t][2]), f2b(acc[i][t][3]));
          *(u32x2*)dstp = wv;
        } else {
#pragma unroll
          for (int j = 0; j < 4; ++j)
            if (cp0 + j < nv) dstp[j] = f2b(acc[i][t][j]);
        }
      }
  }
}

// ---------------------------------------------------------------------------
// Kernel 3: flash attention over COMPACTED keys (unchanged, verified).
// ---------------------------------------------------------------------------
__global__ __launch_bounds__(256) void attn_k(
    const u16* __restrict__ Q, const u16* __restrict__ Kt, const u16* __restrict__ Vt,
    const float* __restrict__ cbias, const int* __restrict__ ntb,
    u16* __restrict__ Xf)
{
  __shared__ u16 Ls[2][8192];  // per buf: [0,4096) K image tile, [4096,8192) V

  const int tid = threadIdx.x;
  const int w = tid >> 6, l = tid & 63, lg = l >> 4, ll = l & 15;
  const int qb = blockIdx.x, h = blockIdx.y, b = blockIdx.z;
  const size_t qbase = (size_t)(b * 16 + h) * 2048 * 64;
  const size_t tbase = (size_t)((b * 16 + h) * 32) * 4096;
  const int q0 = qb * 128 + w * 32;   // wave covers q rows q0 .. q0+31
  const int ntiles = ntb[b];

  short8 aq[2][2];  // [q-group][k-half]
#pragma unroll
  for (int g = 0; g < 2; ++g)
#pragma unroll
    for (int s = 0; s < 2; ++s) {
      V16 v; v.u = *(const u32x4*)&Q[qbase + (size_t)(q0 + g * 16 + ll) * 64 + s * 32 + lg * 8];
      aq[g][s] = v.s;
    }

  float lrow[2] = {0.f, 0.f};
  f32x4 o[2][4];
#pragma unroll
  for (int g = 0; g < 2; ++g)
#pragma unroll
    for (int td = 0; td < 4; ++td) o[g][td] = (f32x4){0.f, 0.f, 0.f, 0.f};

  u32x4 rg[4];
#pragma unroll
  for (int q = 0; q < 4; ++q) {
    const int c = w * 4 + q;
    const u16* src = (c < 8) ? Kt : Vt;
    rg[q] = *(const u32x4*)&src[tbase + (c & 7) * 512 + l * 8];
  }
#pragma unroll
  for (int q = 0; q < 4; ++q)
    *(u32x4*)&Ls[0][(w * 4 + q) * 512 + l * 8] = rg[q];
  if (ntiles > 1) {
#pragma unroll
    for (int q = 0; q < 4; ++q) {
      const int c = w * 4 + q;
      const u16* src = (c < 8) ? Kt : Vt;
      rg[q] = *(const u32x4*)&src[tbase + 4096 + (c & 7) * 512 + l * 8];
    }
  }
  asm volatile("s_waitcnt lgkmcnt(0)" ::: "memory");
  __builtin_amdgcn_sched_barrier(0);
  __builtin_amdgcn_s_barrier();
  __builtin_amdgcn_sched_barrier(0);

  for (int kt = 0; kt < ntiles; ++kt) {
    const int cur = kt & 1;
    const int j0 = kt * 64;
    const u16* Lc = Ls[cur];

    f32x4 sc[2][4];
    __builtin_amdgcn_s_setprio(1);
#pragma unroll
    for (int t = 0; t < 4; ++t) {
      short8 bk0, bk1;
      { V16 v; v.u = *(const u32x4*)&Lc[(t * 2 + 0) * 512 + l * 8]; bk0 = v.s; }
      { V16 v; v.u = *(const u32x4*)&Lc[(t * 2 + 1) * 512 + l * 8]; bk1 = v.s; }
      f32x4 a0 = (f32x4){0.f, 0.f, 0.f, 0.f};
      f32x4 a1 = (f32x4){0.f, 0.f, 0.f, 0.f};
      a0 = __builtin_amdgcn_mfma_f32_16x16x32_bf16(bk0, aq[0][0], a0, 0, 0, 0);
      a1 = __builtin_amdgcn_mfma_f32_16x16x32_bf16(bk0, aq[1][0], a1, 0, 0, 0);
      a0 = __builtin_amdgcn_mfma_f32_16x16x32_bf16(bk1, aq[0][1], a0, 0, 0, 0);
      a1 = __builtin_amdgcn_mfma_f32_16x16x32_bf16(bk1, aq[1][1], a1, 0, 0, 0);
      const f32x4 cb = *(const f32x4*)&cbias[b * 2048 + j0 + ((t >> 1) << 5) + ((t & 1) << 2) + (lg << 3)];
#pragma unroll
      for (int j = 0; j < 4; ++j) {
        sc[0][t][j] = a0[j] + cb[j];
        sc[1][t][j] = a1[j] + cb[j];
      }
    }
    __builtin_amdgcn_s_setprio(0);

#pragma unroll
    for (int g = 0; g < 2; ++g) {
      f32x4 s4 = (f32x4){0.f, 0.f, 0.f, 0.f};
#pragma unroll
      for (int t = 0; t < 4; ++t)
#pragma unroll
        for (int j = 0; j < 4; ++j) {
          sc[g][t][j] = ex2(sc[g][t][j]);
          s4[j] += sc[g][t][j];
        }
      float rs = (s4[0] + s4[1]) + (s4[2] + s4[3]);
      rs += __shfl_xor(rs, 16);
      rs += __shfl_xor(rs, 32);
      lrow[g] += rs;
    }

    __builtin_amdgcn_s_setprio(1);
#pragma unroll
    for (int s = 0; s < 2; ++s) {
      V16 pb0, pb1;
      pb0.u[0] = cvtpk(sc[0][2 * s][0], sc[0][2 * s][1]);
      pb0.u[1] = cvtpk(sc[0][2 * s][2], sc[0][2 * s][3]);
      pb0.u[2] = cvtpk(sc[0][2 * s + 1][0], sc[0][2 * s + 1][1]);
      pb0.u[3] = cvtpk(sc[0][2 * s + 1][2], sc[0][2 * s + 1][3]);
      pb1.u[0] = cvtpk(sc[1][2 * s][0], sc[1][2 * s][1]);
      pb1.u[1] = cvtpk(sc[1][2 * s][2], sc[1][2 * s][3]);
      pb1.u[2] = cvtpk(sc[1][2 * s + 1][0], sc[1][2 * s + 1][1]);
      pb1.u[3] = cvtpk(sc[1][2 * s + 1][2], sc[1][2 * s + 1][3]);
#pragma unroll
      for (int td = 0; td < 4; ++td) {
        V16 v; v.u = *(const u32x4*)&Lc[4096 + (s * 4 + td) * 512 + l * 8];
        o[0][td] = __builtin_amdgcn_mfma_f32_16x16x32_bf16(v.s, pb0.s, o[0][td], 0, 0, 0);
        o[1][td] = __builtin_amdgcn_mfma_f32_16x16x32_bf16(v.s, pb1.s, o[1][td], 0, 0, 0);
      }
    }
    __builtin_amdgcn_s_setprio(0);

    if (kt + 1 < ntiles) {
#pragma unroll
      for (int q = 0; q < 4; ++q)
        *(u32x4*)&Ls[cur ^ 1][(w * 4 + q) * 512 + l * 8] = rg[q];
    }
    if (kt + 2 < ntiles) {
#pragma unroll
      for (int q = 0; q < 4; ++q) {
        const int c = w * 4 + q;
        const u16* src = (c < 8) ? Kt : Vt;
        rg[q] = *(const u32x4*)&src[tbase + (size_t)(kt + 2) * 4096 + (c & 7) * 512 + l * 8];
      }
    }
    asm volatile("s_waitcnt lgkmcnt(0)" ::: "memory");
    __builtin_amdgcn_sched_barrier(0);
    __builtin_amdgcn_s_barrier();
    __builtin_amdgcn_sched_barrier(0);
  }

#pragma unroll
  for (int g = 0; g < 2; ++g) {
    const float inv2 = 1.f / lrow[g];
    const int m = b * 2048 + q0 + g * 16 + ll;
    const int mt = m >> 7, mr = m & 127;
    const int e0 = (lg & 1) * 4;
#pragma unroll
    for (int td = 0; td < 4; ++td) {
      const int c = ((mr >> 6) << 3) | (((mr >> 4) & 3) << 1) | (td >> 1);
      const int lA = (((td << 1) + (lg >> 1)) & 3) * 16 + (mr & 15);
      u32x2 wv;
      wv[0] = cvtpk(o[g][td][0] * inv2, o[g][td][1] * inv2);
      wv[1] = cvtpk(o[g][td][2] * inv2, o[g][td][3] * inv2);
      *(u32x2*)&Xf[((size_t)(mt * 16 + h) * 16 + c) * 512 + lA * 8 + e0] = wv;
    }
  }
}

// ---------------------------------------------------------------------------
// Kernel 4: output GEMM + bias (3-buffer, counted vmcnt(4), depth-2 prefetch
// -- correct schedule for 1 block/CU grid of 256).
// ---------------------------------------------------------------------------
__global__ __launch_bounds__(512, 4) void gemm_out_k(
    const u16* __restrict__ Xf, const u16* __restrict__ WoF,
    const float* __restrict__ bo, float* __restrict__ out)
{
  __shared__ u16 As[3][8192];
  __shared__ u16 Bs[3][8192];

  const int L = blockIdx.x;
  const int xcd = L & 7, idx = L >> 3;
  const int mt = (xcd << 2) | (idx & 3);
  const int nt = idx >> 2;

  const int tid = threadIdx.x;
  const int w = tid >> 6, l = tid & 63, lg = l >> 4, ll = l & 15;
  const int wr = w >> 2, wc = w & 3;
  const size_t ab = (size_t)mt * 131072;
  const size_t bb = (size_t)nt * 131072;

  f32x4 acc[4][2];
#pragma unroll
  for (int i = 0; i < 4; ++i)
#pragma unroll
    for (int t = 0; t < 2; ++t)
      acc[i][t] = (f32x4){0.f, 0.f, 0.f, 0.f};

#define OUT_ISSUE(ksx, buf) do {                                           \
    const size_t ao_ = ab + (size_t)(ksx) * 8192;                          \
    const size_t bo_ = bb + (size_t)(ksx) * 8192;                          \
    gld16(Xf + ao_ + (size_t)w * 512 + l * 8,        &As[buf][w * 512]);   \
    gld16(Xf + ao_ + (size_t)(w + 8) * 512 + l * 8,  &As[buf][(w + 8) * 512]); \
    gld16(WoF + bo_ + (size_t)w * 512 + l * 8,       &Bs[buf][w * 512]);   \
    gld16(WoF + bo_ + (size_t)(w + 8) * 512 + l * 8, &Bs[buf][(w + 8) * 512]); \
  } while (0)

  OUT_ISSUE(0, 0);
  OUT_ISSUE(1, 1);

  for (int ks = 0; ks < 16; ++ks) {
    const int cur = ks % 3;
    if (ks < 15) asm volatile("s_waitcnt vmcnt(4)" ::: "memory");
    else         asm volatile("s_waitcnt vmcnt(0)" ::: "memory");
    __builtin_amdgcn_sched_barrier(0);
    __builtin_amdgcn_s_barrier();
    __builtin_amdgcn_sched_barrier(0);

    if (ks + 2 < 16) OUT_ISSUE(ks + 2, (ks + 2) % 3);

    short8 afr[2][4], bfr[2][2];
#pragma unroll
    for (int kk = 0; kk < 2; ++kk) {
#pragma unroll
      for (int i = 0; i < 4; ++i) {
        V16 v; v.u = *(const u32x4*)&As[cur][(wr * 8 + i * 2 + kk) * 512 + l * 8];
        afr[kk][i] = v.s;
      }
#pragma unroll
      for (int t = 0; t < 2; ++t) {
        V16 v; v.u = *(const u32x4*)&Bs[cur][((wc >> 1) * 8 + ((wc & 1) * 2 + t) * 2 + kk) * 512 + l * 8];
        bfr[kk][t] = v.s;
      }
    }
#pragma unroll
    for (int kk = 0; kk < 2; ++kk)
#pragma unroll
      for (int i = 0; i < 4; ++i)
#pragma unroll
        for (int t = 0; t < 2; ++t)
          acc[i][t] = __builtin_amdgcn_mfma_f32_16x16x32_bf16(afr[kk][i], bfr[kk][t], acc[i][t], 0, 0, 0);
  }
#undef OUT_ISSUE

  const int m0 = mt * 128, n0 = nt * 128;
#pragma unroll
  for (int i = 0; i < 4; ++i)
#pragma unroll
    for (int t = 0; t < 2; ++t) {
      const int n = n0 + wc * 32 + t * 16 + ll;
      const float bv = bo[n];
#pragma unroll
      for (int j = 0; j < 4; ++j) {
        const int m = m0 + wr * 64 + i * 16 + lg * 4 + j;
        out[(size_t)m * 1024 + n] = acc[i][t][j] + bv;
      }
    }
}

// ---------------------------------------------------------------------------
extern "C" void kernel_launch(void* const* d_in, const int* in_sizes, int n_in,
                              void* d_out, int out_size, void* d_ws, size_t ws_size,
                              hipStream_t stream) {
  const float* qry = (const float*)d_in[0];
  const float* key = (const float*)d_in[1];
  const float* val = (const float*)d_in[2];
  const int* mask  = (const int*)d_in[3];
  const float* Wq  = (const float*)d_in[4];
  const float* Wk  = (const float*)d_in[5];
  const float* Wv  = (const float*)d_in[6];
  const float* Wo  = (const float*)d_in[7];
  const float* bo  = (const float*)d_in[8];
  float* out = (float*)d_out;

  char* ws = (char*)d_ws;
  u16* Wt  = (u16*)(ws);                 // [0,6M)   weight B images (q,k,v)
  u16* WoT = (u16*)(ws + 6291456);       // [6M,8M)  Wo B image
  u16* Qw  = (u16*)(ws + 8388608);       // [8M,16M)  Q [b][h][n][64]
  u16* Kw  = (u16*)(ws + 16777216);      // [16M,24M) K compacted fragment images
  u16* Vw  = (u16*)(ws + 25165824);      // [24M,32M) V compacted fragment images
  u16* Af  = (u16*)(ws + 33554432);      // A images: 24MB (big) or 8MB (small)
  u16* Xw  = (u16*)(ws + 33554432);      // X image (overlaps Af; Af dead by attn)

  // compaction scratch lives in d_out (overwritten by gemm_out at the end)
  int*   inv   = (int*)d_out;                       // 16 KB (compact -> orig)
  float* cbias = (float*)((char*)d_out + 16384);    // 16 KB
  int*   ntb   = (int*)((char*)d_out + 32768);      // 16 B: [0..1]=ntiles, [2..3]=nvalid

  maskscan<<<dim3(16, 2), 256, 0, stream>>>(mask, inv, cbias, ntb, Kw, Vw);

  const bool big = (ws_size >= 58720256ull);
  if (big) {
    convfuse<<<dim3(16, 32, 7), 256, 0, stream>>>(
        Wq, Wk, Wv, Wo, Wt, WoT, qry, key, val, Af, inv, ntb, 4194304);
    gemm_qkv_k<<<dim3(768, 1, 1), 512, 0, stream>>>(Af, Wt, Qw, Kw, Vw, ntb, 0, 4194304);
  } else {
    // small-path: weights (z=0..3) then per-z activations + GEMM
    convfuse<<<dim3(16, 32, 4), 256, 0, stream>>>(
        Wq, Wk, Wv, Wo, Wt, WoT, qry, key, val, Af, inv, ntb, 0);
    for (int z = 0; z < 3; ++z) {
      convfuse<<<dim3(16, 32, 1), 256, 0, stream>>>(
          Wq, Wk, Wv, Wo, Wt, WoT,
          (z == 0) ? qry : (z == 1) ? key : val,
          key, val, Af, inv, ntb, 0);  // za=0 path writes Af slice 0; gather handled below
      gemm_qkv_k<<<dim3(256, 1, 1), 512, 0, stream>>>(Af, Wt, Qw, Kw, Vw, ntb, z, 0);
    }
  }
  attn_k<<<dim3(16, 16, 2), 256, 0, stream>>>(Qw, Kw, Vw, cbias, ntb, Xw);
  gemm_out_k<<<dim3(256, 1, 1), 512, 0, stream>>>(Xw, WoT, bo, out);
}

// Round 26
// 97.861 us; speedup vs baseline: 1.0419x; 1.0419x over previous
//
#include <hip/hip_runtime.h>
#include <hip/hip_bf16.h>

using u16 = unsigned short;
using u32 = unsigned int;
using short8 = __attribute__((ext_vector_type(8))) short;  // 8 bf16
using f32x4  = __attribute__((ext_vector_type(4))) float;
using u32x4  = __attribute__((ext_vector_type(4))) u32;
using u32x2  = __attribute__((ext_vector_type(2))) u32;

union V16 { u32x4 u; short8 s; };

__device__ __forceinline__ u16 f2b(float f) {
  u32 u = __float_as_uint(f);
  u32 r = (u + 0x7FFFu + ((u >> 16) & 1u)) >> 16;
  return (u16)r;
}
__device__ __forceinline__ u32 pk2(u16 a, u16 b) {
  return (u32)a | ((u32)b << 16);
}
// packed f32->bf16 pair (RNE), single VOP3 instr (no builtin on gfx950)
__device__ __forceinline__ u32 cvtpk(float lo, float hi) {
  u32 r;
  asm("v_cvt_pk_bf16_f32 %0, %1, %2" : "=v"(r) : "v"(lo), "v"(hi));
  return r;
}
// raw 2^x (v_exp_f32 computes exp2 natively)
__device__ __forceinline__ float ex2(float x) {
  float r;
  asm("v_exp_f32 %0, %1" : "=v"(r) : "v"(x));
  return r;
}
// async global->LDS, 16B per lane; dest = wave-uniform base + lane*16 (linear)
__device__ __forceinline__ void gld16(const u16* g, u16* l) {
  __builtin_amdgcn_global_load_lds(
      (const __attribute__((address_space(1))) u32*)g,
      (__attribute__((address_space(3))) u32*)l, 16, 0, 0);
}

#define KSCALE 0.18033688011f  // 0.125 * log2(e): folds attn scale into exp2 domain
#define SMAX   12.0f           // static softmax shift (folded into cbias)

// Fragment-image layout (shared by all GEMM operands):
//   img[(tile128*16 + ks)*16 + c][l][e],  c=chunk 0..15, l=lane 0..63, e=0..7
//   c = o*8 + f*2 + kk:  row(tile-local) = o*64 + f*16 + (l&15)
//                        col(k)          = ks*64 + kk*32 + (l>>4)*8 + e

// ---------------------------------------------------------------------------
// Kernel 1: weight -> bf16 fragment image (B operand).
// ---------------------------------------------------------------------------
__global__ __launch_bounds__(256) void wconv(
    const float* __restrict__ Wq, const float* __restrict__ Wk,
    const float* __restrict__ Wv, const float* __restrict__ Wo,
    u16* __restrict__ Wt, u16* __restrict__ WoT)
{
  __shared__ u16 T[64][130];
  const int zz = blockIdx.z;
  const float* src = (zz == 0) ? Wq : (zz == 1) ? Wk : (zz == 2) ? Wv : Wo;
  u16* dst = (zz < 3) ? (Wt + (size_t)zz * 1048576) : WoT;
  const int nt = blockIdx.x, ks = blockIdx.y;
  const int tid = threadIdx.x;

  {
    const int kl = tid >> 2, nl0 = (tid & 3) * 32;
    const float* sp = src + (size_t)(ks * 64 + kl) * 1024 + nt * 128 + nl0;
#pragma unroll
    for (int i = 0; i < 8; ++i) {
      f32x4 x = *(const f32x4*)(sp + i * 4);
      T[kl][nl0 + i * 4 + 0] = f2b(x[0]);
      T[kl][nl0 + i * 4 + 1] = f2b(x[1]);
      T[kl][nl0 + i * 4 + 2] = f2b(x[2]);
      T[kl][nl0 + i * 4 + 3] = f2b(x[3]);
    }
  }
  __syncthreads();

  const int c = tid >> 4, l0 = (tid & 15) * 4;
  u16* dp = dst + ((size_t)(nt * 16 + ks) * 16 + c) * 512 + l0 * 8;
#pragma unroll
  for (int dl = 0; dl < 4; ++dl) {
    const int l = l0 + dl;
    const int kl = (c & 1) * 32 + (l >> 4) * 8;
    const int nl = (c >> 3) * 64 + ((c >> 1) & 3) * 16 + (l & 15);
    u32x4 u;
#pragma unroll
    for (int p = 0; p < 4; ++p)
      u[p] = pk2(T[kl + 2 * p][nl], T[kl + 2 * p + 1][nl]);
    *(u32x4*)(dp + dl * 8) = u;
  }
}

// ---------------------------------------------------------------------------
// Kernel 1b: maskscan — per-batch compaction.  Grid (16 heads, 2 batch).
// h==0 writes inv (compact->orig map), cbias, ntb[b]=ntiles, ntb[2+b]=nvalid.
// Every block zeroes its head's K/V image pad slots (keys nvalid..pad64).
// ---------------------------------------------------------------------------
__global__ __launch_bounds__(256) void maskscan(
    const int* __restrict__ mask, int* __restrict__ inv,
    float* __restrict__ cbias, int* __restrict__ ntb,
    u16* __restrict__ Kimg, u16* __restrict__ Vimg)
{
  const int h = blockIdx.x, b = blockIdx.y;
  const int tid = threadIdx.x;
  __shared__ int ssum[256];

  int m8[8], s = 0;
#pragma unroll
  for (int i = 0; i < 8; ++i) {
    m8[i] = mask[b * 2048 + tid * 8 + i] ? 1 : 0;
    s += m8[i];
  }
  ssum[tid] = s;
  __syncthreads();
  for (int off = 1; off < 256; off <<= 1) {
    int v = (tid >= off) ? ssum[tid - off] : 0;
    __syncthreads();
    ssum[tid] += v;
    __syncthreads();
  }
  const int nvalid = ssum[255];
  int run = ssum[tid] - s;  // exclusive prefix

  if (h == 0) {
    int run2 = run;
#pragma unroll
    for (int i = 0; i < 8; ++i) {
      if (m8[i]) { inv[b * 2048 + run2] = tid * 8 + i; ++run2; }
    }
#pragma unroll
    for (int i = 0; i < 8; ++i) {
      const int idx = tid * 8 + i;
      cbias[b * 2048 + idx] = (idx < nvalid) ? -SMAX : -1e30f;
    }
    if (tid == 0) { ntb[b] = (nvalid + 63) >> 6; ntb[2 + b] = nvalid; }
  }

  // zero K/V pad slots for this head (keys nvalid .. pad64-1)
  const int pend = ((nvalid + 63) >> 6) << 6;
  for (int p = nvalid + tid; p < pend; p += 256) {
    const int kt2 = p >> 6, r = p & 63;
    const size_t base = ((size_t)((b * 16 + h) * 32 + kt2)) * 4096;
    const int t2 = ((r >> 5) << 1) | ((r >> 2) & 1);
    const int ll2 = (((r >> 3) & 3) << 2) | (r & 3);
#pragma unroll
    for (int s2 = 0; s2 < 2; ++s2)
#pragma unroll
      for (int lgk = 0; lgk < 4; ++lgk)
#pragma unroll
        for (int e = 0; e < 8; ++e)
          Kimg[base + (t2 * 2 + s2) * 512 + (lgk * 16 + ll2) * 8 + e] = 0;
    const int sv = r >> 5, lgv = (r >> 3) & 3, e0 = r & 7;
#pragma unroll
    for (int td = 0; td < 4; ++td)
#pragma unroll
      for (int llv = 0; llv < 16; ++llv)
        Vimg[base + (sv * 4 + td) * 512 + (lgv * 16 + llv) * 8 + e0] = 0;
  }
}

// ---------------------------------------------------------------------------
// Kernel 1c: activation f32 -> bf16 fragment image (A operand).
// z=0 (qry): identity rows.  z>=1 (key/val): COMPACTED rows — dest row cpos
// gathers source row inv[cpos]; rows >= nvalid skipped.
// ---------------------------------------------------------------------------
__global__ __launch_bounds__(256) void aconv(
    const float* __restrict__ Aq, const float* __restrict__ Ak,
    const float* __restrict__ Av, u16* __restrict__ Af,
    const int* __restrict__ inv, const int* __restrict__ ntbv,
    int z0, size_t zstride)
{
  const int z = blockIdx.z + z0;
  const float* A = (z == 0) ? Aq : (z == 1) ? Ak : Av;
  u16* dst = Af + (size_t)blockIdx.z * zstride;
  const int ks = blockIdx.x, mt = blockIdx.y;
  const int tid = threadIdx.x;
  const int r = tid >> 1, h = tid & 1;

  int srow = mt * 128 + r;
  if (z >= 1) {
    const int b = srow >> 11, cpos = srow & 2047;
    if (cpos >= ntbv[2 + b]) return;           // beyond valid keys: skip
    srow = b * 2048 + inv[b * 2048 + cpos];    // gather original row
  }

  const f32x4* sp = (const f32x4*)(A + (size_t)srow * 1024 + ks * 64 + h * 32);
  const int c = ((r >> 6) << 3) | (((r >> 4) & 3) << 1) | h;
  u16* dp = dst + ((size_t)(mt * 16 + ks) * 16 + c) * 512 + (r & 15) * 8;

#pragma unroll
  for (int lg = 0; lg < 4; ++lg) {
    f32x4 x0 = sp[2 * lg], x1 = sp[2 * lg + 1];
    u32x4 u;
    u[0] = cvtpk(x0[0], x0[1]); u[1] = cvtpk(x0[2], x0[3]);
    u[2] = cvtpk(x1[0], x1[1]); u[3] = cvtpk(x1[2], x1[3]);
    *(u32x4*)(dp + lg * 128) = u;
  }
}

// ---------------------------------------------------------------------------
// Kernel 2: QKV projection GEMM.  BK=32, 3-buffer LDS (48KB -> 3 blocks/CU),
// ONE barrier per step, depth-2 prefetch with counted vmcnt(2):
//   vmcnt(2) [step-s loads done, s+1's 2 in flight] -> barrier -> issue step
//   s+2 into buf[(s+2)%3] (read at step s-1; barrier proved reads done) ->
//   ds_read (4 A + 2 B frags) + 8 MFMA.  32 steps, 32 barriers total.
// z-dependent XCD map; compacted K/V with early-exit and guarded epilogues.
// ---------------------------------------------------------------------------
__global__ __launch_bounds__(512, 4) void gemm_qkv_k(
    const u16* __restrict__ Af, const u16* __restrict__ Wt,
    u16* __restrict__ Qw, u16* __restrict__ Kw, u16* __restrict__ Vw,
    const int* __restrict__ ntbv, int z0, size_t azs)
{
  __shared__ u16 As[3][4096];   // 8 chunks x 512 (BK=32 A tile)
  __shared__ u16 Bs[3][4096];   // 8 chunks x 512 (BK=32 B tile)

  const int L = blockIdx.x;
  const int xcd = L & 7, idx = L >> 3;
  const int zi = idx >> 5;
  const int z = z0 + zi;
  const int mt = (z == 0) ? ((xcd << 2) | (idx & 3))     // Q: XCD-local A
                          : (((idx & 3) << 3) | xcd);    // K/V: spread valid mts
  const int nt = (idx >> 2) & 7;

  // compacted K/V: skip tiles entirely beyond this batch's valid rows
  if (z >= 1) {
    const int b0 = (mt * 128) >> 11;
    if ((mt * 128 & 2047) >= ntbv[2 + b0]) return;
  }

  const u16* Aimg = Af + (size_t)zi * azs;
  const u16* Bimg = Wt + (size_t)z * 1048576;
  u16* O = (z == 0) ? Qw : (z == 1) ? Kw : Vw;

  const int tid = threadIdx.x;
  const int w = tid >> 6, l = tid & 63, lg = l >> 4, ll = l & 15;
  const int wr = w >> 2, wc = w & 3;
  const size_t ab = (size_t)mt * 131072;
  const size_t bb = (size_t)nt * 131072;

  f32x4 acc[4][2];
#pragma unroll
  for (int i = 0; i < 4; ++i)
#pragma unroll
    for (int t = 0; t < 2; ++t)
      acc[i][t] = (f32x4){0.f, 0.f, 0.f, 0.f};

  // step sx = ks64*2 + kk selects the 8 chunks c = o*8+f*2+kk of K-step ks64.
  // wave w stages dest chunk w (o=w>>2, f=w&3) for both A and B: 2 gld16/wave.
#define QKV_ISSUE(sx, bf) do {                                              \
    const int ksi_ = (sx) >> 1, kkx_ = (sx) & 1;                            \
    const size_t off_ = (size_t)ksi_ * 8192 +                               \
        (size_t)(((w >> 2) * 8) + ((w & 3) * 2) + kkx_) * 512 + l * 8;      \
    gld16(Aimg + ab + off_, &As[bf][w * 512]);                              \
    gld16(Bimg + bb + off_, &Bs[bf][w * 512]);                              \
  } while (0)

  QKV_ISSUE(0, 0);
  QKV_ISSUE(1, 1);

  for (int s = 0; s < 32; ++s) {
    const int cur = s % 3;
    if (s < 31) asm volatile("s_waitcnt vmcnt(2)" ::: "memory");  // own tile done
    else        asm volatile("s_waitcnt vmcnt(0)" ::: "memory");
    __builtin_amdgcn_sched_barrier(0);
    __builtin_amdgcn_s_barrier();   // publishes step-s; proves s-1 reads done
    __builtin_amdgcn_sched_barrier(0);

    if (s + 2 < 32) QKV_ISSUE(s + 2, (s + 2) % 3);

    short8 afr[4], bfr[2];
#pragma unroll
    for (int i = 0; i < 4; ++i) {
      V16 v; v.u = *(const u32x4*)&As[cur][(wr * 4 + i) * 512 + l * 8];
      afr[i] = v.s;
    }
#pragma unroll
    for (int t = 0; t < 2; ++t) {
      V16 v; v.u = *(const u32x4*)&Bs[cur][((wc >> 1) * 4 + (wc & 1) * 2 + t) * 512 + l * 8];
      bfr[t] = v.s;
    }
#pragma unroll
    for (int i = 0; i < 4; ++i)
#pragma unroll
      for (int t = 0; t < 2; ++t)
        acc[i][t] = __builtin_amdgcn_mfma_f32_16x16x32_bf16(afr[i], bfr[t], acc[i][t], 0, 0, 0);
  }
#undef QKV_ISSUE

  const int m0 = mt * 128, n0 = nt * 128;
  if (z == 0) {
#pragma unroll
    for (int i = 0; i < 4; ++i)
#pragma unroll
      for (int t = 0; t < 2; ++t) {
        const int n = n0 + wc * 32 + t * 16 + ll;
        const int h = n >> 6, dd = n & 63;
#pragma unroll
        for (int j = 0; j < 4; ++j) {
          const int m = m0 + wr * 64 + i * 16 + lg * 4 + j;
          const int bbk = m >> 11, pos = m & 2047;
          O[((size_t)(bbk * 16 + h) * 2048 + pos) * 64 + dd] = f2b(acc[i][t][j]);
        }
      }
  } else if (z == 1) {
    const int bbk = m0 >> 11;
    const int nv = ntbv[2 + bbk];
#pragma unroll
    for (int i = 0; i < 4; ++i)
#pragma unroll
      for (int t = 0; t < 2; ++t) {
        const int n = n0 + wc * 32 + t * 16 + ll;
        const int h = n >> 6, dd = n & 63;
        const int s = dd >> 5, lgk = (dd >> 3) & 3, e = dd & 7;
#pragma unroll
        for (int j = 0; j < 4; ++j) {
          const int m = m0 + wr * 64 + i * 16 + lg * 4 + j;
          const int cpos = m & 2047;
          if (cpos < nv) {
            const int kt2 = cpos >> 6, r = cpos & 63;
            const int t2 = ((r >> 5) << 1) | ((r >> 2) & 1);
            const int ll2 = (((r >> 3) & 3) << 2) | (r & 3);
            O[((size_t)((bbk * 16 + h) * 32 + kt2)) * 4096 + (t2 * 2 + s) * 512 + (lgk * 16 + ll2) * 8 + e]
                = f2b(acc[i][t][j] * KSCALE);
          }
        }
      }
  } else {
    const int bbk = m0 >> 11;
    const int nv = ntbv[2 + bbk];
#pragma unroll
    for (int i = 0; i < 4; ++i)
#pragma unroll
      for (int t = 0; t < 2; ++t) {
        const int n = n0 + wc * 32 + t * 16 + ll;
        const int h = n >> 6, dd = n & 63;
        const int td = dd >> 4, llv = dd & 15;
        const int mb0 = m0 + wr * 64 + i * 16 + lg * 4;   // j = 0
        const int cp0 = mb0 & 2047;
        const int kt2 = cp0 >> 6, kk = cp0 & 63;
        const int s = kk >> 5, lgv = (kk >> 3) & 3, e0 = kk & 7;
        u16* dstp = &O[((size_t)((bbk * 16 + h) * 32 + kt2)) * 4096 + (s * 4 + td) * 512 + (lgv * 16 + llv) * 8 + e0];
        if (cp0 + 3 < nv) {
          u32x2 wv;
          wv[0] = pk2(f2b(acc[i][t][0]), f2b(acc[i][t][1]));
          wv[1] = pk2(f2b(acc[i][t][2]), f2b(acc[i][t][3]));
          *(u32x2*)dstp = wv;
        } else {
#pragma unroll
          for (int j = 0; j < 4; ++j)
            if (cp0 + j < nv) dstp[j] = f2b(acc[i][t][j]);
        }
      }
  }
}

// ---------------------------------------------------------------------------
// Kernel 3: flash attention over COMPACTED keys (unchanged, verified).
// ---------------------------------------------------------------------------
__global__ __launch_bounds__(256) void attn_k(
    const u16* __restrict__ Q, const u16* __restrict__ Kt, const u16* __restrict__ Vt,
    const float* __restrict__ cbias, const int* __restrict__ ntb,
    u16* __restrict__ Xf)
{
  __shared__ u16 Ls[2][8192];  // per buf: [0,4096) K image tile, [4096,8192) V

  const int tid = threadIdx.x;
  const int w = tid >> 6, l = tid & 63, lg = l >> 4, ll = l & 15;
  const int qb = blockIdx.x, h = blockIdx.y, b = blockIdx.z;
  const size_t qbase = (size_t)(b * 16 + h) * 2048 * 64;
  const size_t tbase = (size_t)((b * 16 + h) * 32) * 4096;
  const int q0 = qb * 128 + w * 32;   // wave covers q rows q0 .. q0+31
  const int ntiles = ntb[b];

  short8 aq[2][2];  // [q-group][k-half]
#pragma unroll
  for (int g = 0; g < 2; ++g)
#pragma unroll
    for (int s = 0; s < 2; ++s) {
      V16 v; v.u = *(const u32x4*)&Q[qbase + (size_t)(q0 + g * 16 + ll) * 64 + s * 32 + lg * 8];
      aq[g][s] = v.s;
    }

  float lrow[2] = {0.f, 0.f};
  f32x4 o[2][4];
#pragma unroll
  for (int g = 0; g < 2; ++g)
#pragma unroll
    for (int td = 0; td < 4; ++td) o[g][td] = (f32x4){0.f, 0.f, 0.f, 0.f};

  u32x4 rg[4];
#pragma unroll
  for (int q = 0; q < 4; ++q) {
    const int c = w * 4 + q;
    const u16* src = (c < 8) ? Kt : Vt;
    rg[q] = *(const u32x4*)&src[tbase + (c & 7) * 512 + l * 8];
  }
#pragma unroll
  for (int q = 0; q < 4; ++q)
    *(u32x4*)&Ls[0][(w * 4 + q) * 512 + l * 8] = rg[q];
  if (ntiles > 1) {
#pragma unroll
    for (int q = 0; q < 4; ++q) {
      const int c = w * 4 + q;
      const u16* src = (c < 8) ? Kt : Vt;
      rg[q] = *(const u32x4*)&src[tbase + 4096 + (c & 7) * 512 + l * 8];
    }
  }
  asm volatile("s_waitcnt lgkmcnt(0)" ::: "memory");
  __builtin_amdgcn_sched_barrier(0);
  __builtin_amdgcn_s_barrier();
  __builtin_amdgcn_sched_barrier(0);

  for (int kt = 0; kt < ntiles; ++kt) {
    const int cur = kt & 1;
    const int j0 = kt * 64;
    const u16* Lc = Ls[cur];

    f32x4 sc[2][4];
    __builtin_amdgcn_s_setprio(1);
#pragma unroll
    for (int t = 0; t < 4; ++t) {
      short8 bk0, bk1;
      { V16 v; v.u = *(const u32x4*)&Lc[(t * 2 + 0) * 512 + l * 8]; bk0 = v.s; }
      { V16 v; v.u = *(const u32x4*)&Lc[(t * 2 + 1) * 512 + l * 8]; bk1 = v.s; }
      f32x4 a0 = (f32x4){0.f, 0.f, 0.f, 0.f};
      f32x4 a1 = (f32x4){0.f, 0.f, 0.f, 0.f};
      a0 = __builtin_amdgcn_mfma_f32_16x16x32_bf16(bk0, aq[0][0], a0, 0, 0, 0);
      a1 = __builtin_amdgcn_mfma_f32_16x16x32_bf16(bk0, aq[1][0], a1, 0, 0, 0);
      a0 = __builtin_amdgcn_mfma_f32_16x16x32_bf16(bk1, aq[0][1], a0, 0, 0, 0);
      a1 = __builtin_amdgcn_mfma_f32_16x16x32_bf16(bk1, aq[1][1], a1, 0, 0, 0);
      const f32x4 cb = *(const f32x4*)&cbias[b * 2048 + j0 + ((t >> 1) << 5) + ((t & 1) << 2) + (lg << 3)];
#pragma unroll
      for (int j = 0; j < 4; ++j) {
        sc[0][t][j] = a0[j] + cb[j];
        sc[1][t][j] = a1[j] + cb[j];
      }
    }
    __builtin_amdgcn_s_setprio(0);

#pragma unroll
    for (int g = 0; g < 2; ++g) {
      f32x4 s4 = (f32x4){0.f, 0.f, 0.f, 0.f};
#pragma unroll
      for (int t = 0; t < 4; ++t)
#pragma unroll
        for (int j = 0; j < 4; ++j) {
          sc[g][t][j] = ex2(sc[g][t][j]);
          s4[j] += sc[g][t][j];
        }
      float rs = (s4[0] + s4[1]) + (s4[2] + s4[3]);
      rs += __shfl_xor(rs, 16);
      rs += __shfl_xor(rs, 32);
      lrow[g] += rs;
    }

    __builtin_amdgcn_s_setprio(1);
#pragma unroll
    for (int s = 0; s < 2; ++s) {
      V16 pb0, pb1;
      pb0.u[0] = cvtpk(sc[0][2 * s][0], sc[0][2 * s][1]);
      pb0.u[1] = cvtpk(sc[0][2 * s][2], sc[0][2 * s][3]);
      pb0.u[2] = cvtpk(sc[0][2 * s + 1][0], sc[0][2 * s + 1][1]);
      pb0.u[3] = cvtpk(sc[0][2 * s + 1][2], sc[0][2 * s + 1][3]);
      pb1.u[0] = cvtpk(sc[1][2 * s][0], sc[1][2 * s][1]);
      pb1.u[1] = cvtpk(sc[1][2 * s][2], sc[1][2 * s][3]);
      pb1.u[2] = cvtpk(sc[1][2 * s + 1][0], sc[1][2 * s + 1][1]);
      pb1.u[3] = cvtpk(sc[1][2 * s + 1][2], sc[1][2 * s + 1][3]);
#pragma unroll
      for (int td = 0; td < 4; ++td) {
        V16 v; v.u = *(const u32x4*)&Lc[4096 + (s * 4 + td) * 512 + l * 8];
        o[0][td] = __builtin_amdgcn_mfma_f32_16x16x32_bf16(v.s, pb0.s, o[0][td], 0, 0, 0);
        o[1][td] = __builtin_amdgcn_mfma_f32_16x16x32_bf16(v.s, pb1.s, o[1][td], 0, 0, 0);
      }
    }
    __builtin_amdgcn_s_setprio(0);

    if (kt + 1 < ntiles) {
#pragma unroll
      for (int q = 0; q < 4; ++q)
        *(u32x4*)&Ls[cur ^ 1][(w * 4 + q) * 512 + l * 8] = rg[q];
    }
    if (kt + 2 < ntiles) {
#pragma unroll
      for (int q = 0; q < 4; ++q) {
        const int c = w * 4 + q;
        const u16* src = (c < 8) ? Kt : Vt;
        rg[q] = *(const u32x4*)&src[tbase + (size_t)(kt + 2) * 4096 + (c & 7) * 512 + l * 8];
      }
    }
    asm volatile("s_waitcnt lgkmcnt(0)" ::: "memory");
    __builtin_amdgcn_sched_barrier(0);
    __builtin_amdgcn_s_barrier();
    __builtin_amdgcn_sched_barrier(0);
  }

#pragma unroll
  for (int g = 0; g < 2; ++g) {
    const float inv2 = 1.f / lrow[g];
    const int m = b * 2048 + q0 + g * 16 + ll;
    const int mt = m >> 7, mr = m & 127;
    const int e0 = (lg & 1) * 4;
#pragma unroll
    for (int td = 0; td < 4; ++td) {
      const int c = ((mr >> 6) << 3) | (((mr >> 4) & 3) << 1) | (td >> 1);
      const int lA = (((td << 1) + (lg >> 1)) & 3) * 16 + (mr & 15);
      u32x2 wv;
      wv[0] = cvtpk(o[g][td][0] * inv2, o[g][td][1] * inv2);
      wv[1] = cvtpk(o[g][td][2] * inv2, o[g][td][3] * inv2);
      *(u32x2*)&Xf[((size_t)(mt * 16 + h) * 16 + c) * 512 + lA * 8 + e0] = wv;
    }
  }
}

// ---------------------------------------------------------------------------
// Kernel 4: output GEMM + bias (3-buffer, counted vmcnt(4), depth-2 prefetch
// -- correct schedule for 1 block/CU grid of 256).
// ---------------------------------------------------------------------------
__global__ __launch_bounds__(512, 4) void gemm_out_k(
    const u16* __restrict__ Xf, const u16* __restrict__ WoF,
    const float* __restrict__ bo, float* __restrict__ out)
{
  __shared__ u16 As[3][8192];
  __shared__ u16 Bs[3][8192];

  const int L = blockIdx.x;
  const int xcd = L & 7, idx = L >> 3;
  const int mt = (xcd << 2) | (idx & 3);
  const int nt = idx >> 2;

  const int tid = threadIdx.x;
  const int w = tid >> 6, l = tid & 63, lg = l >> 4, ll = l & 15;
  const int wr = w >> 2, wc = w & 3;
  const size_t ab = (size_t)mt * 131072;
  const size_t bb = (size_t)nt * 131072;

  f32x4 acc[4][2];
#pragma unroll
  for (int i = 0; i < 4; ++i)
#pragma unroll
    for (int t = 0; t < 2; ++t)
      acc[i][t] = (f32x4){0.f, 0.f, 0.f, 0.f};

#define OUT_ISSUE(ksx, buf) do {                                           \
    const size_t ao_ = ab + (size_t)(ksx) * 8192;                          \
    const size_t bo_ = bb + (size_t)(ksx) * 8192;                          \
    gld16(Xf + ao_ + (size_t)w * 512 + l * 8,        &As[buf][w * 512]);   \
    gld16(Xf + ao_ + (size_t)(w + 8) * 512 + l * 8,  &As[buf][(w + 8) * 512]); \
    gld16(WoF + bo_ + (size_t)w * 512 + l * 8,       &Bs[buf][w * 512]);   \
    gld16(WoF + bo_ + (size_t)(w + 8) * 512 + l * 8, &Bs[buf][(w + 8) * 512]); \
  } while (0)

  OUT_ISSUE(0, 0);
  OUT_ISSUE(1, 1);

  for (int ks = 0; ks < 16; ++ks) {
    const int cur = ks % 3;
    if (ks < 15) asm volatile("s_waitcnt vmcnt(4)" ::: "memory");
    else         asm volatile("s_waitcnt vmcnt(0)" ::: "memory");
    __builtin_amdgcn_sched_barrier(0);
    __builtin_amdgcn_s_barrier();
    __builtin_amdgcn_sched_barrier(0);

    if (ks + 2 < 16) OUT_ISSUE(ks + 2, (ks + 2) % 3);

    short8 afr[2][4], bfr[2][2];
#pragma unroll
    for (int kk = 0; kk < 2; ++kk) {
#pragma unroll
      for (int i = 0; i < 4; ++i) {
        V16 v; v.u = *(const u32x4*)&As[cur][(wr * 8 + i * 2 + kk) * 512 + l * 8];
        afr[kk][i] = v.s;
      }
#pragma unroll
      for (int t = 0; t < 2; ++t) {
        V16 v; v.u = *(const u32x4*)&Bs[cur][((wc >> 1) * 8 + ((wc & 1) * 2 + t) * 2 + kk) * 512 + l * 8];
        bfr[kk][t] = v.s;
      }
    }
#pragma unroll
    for (int kk = 0; kk < 2; ++kk)
#pragma unroll
      for (int i = 0; i < 4; ++i)
#pragma unroll
        for (int t = 0; t < 2; ++t)
          acc[i][t] = __builtin_amdgcn_mfma_f32_16x16x32_bf16(afr[kk][i], bfr[kk][t], acc[i][t], 0, 0, 0);
  }
#undef OUT_ISSUE

  const int m0 = mt * 128, n0 = nt * 128;
#pragma unroll
  for (int i = 0; i < 4; ++i)
#pragma unroll
    for (int t = 0; t < 2; ++t) {
      const int n = n0 + wc * 32 + t * 16 + ll;
      const float bv = bo[n];
#pragma unroll
      for (int j = 0; j < 4; ++j) {
        const int m = m0 + wr * 64 + i * 16 + lg * 4 + j;
        out[(size_t)m * 1024 + n] = acc[i][t][j] + bv;
      }
    }
}

// ---------------------------------------------------------------------------
extern "C" void kernel_launch(void* const* d_in, const int* in_sizes, int n_in,
                              void* d_out, int out_size, void* d_ws, size_t ws_size,
                              hipStream_t stream) {
  const float* qry = (const float*)d_in[0];
  const float* key = (const float*)d_in[1];
  const float* val = (const float*)d_in[2];
  const int* mask  = (const int*)d_in[3];
  const float* Wq  = (const float*)d_in[4];
  const float* Wk  = (const float*)d_in[5];
  const float* Wv  = (const float*)d_in[6];
  const float* Wo  = (const float*)d_in[7];
  const float* bo  = (const float*)d_in[8];
  float* out = (float*)d_out;

  char* ws = (char*)d_ws;
  u16* Wt  = (u16*)(ws);                 // [0,6M)   weight B images (q,k,v)
  u16* WoT = (u16*)(ws + 6291456);       // [6M,8M)  Wo B image
  u16* Qw  = (u16*)(ws + 8388608);       // [8M,16M)  Q [b][h][n][64]
  u16* Kw  = (u16*)(ws + 16777216);      // [16M,24M) K compacted fragment images
  u16* Vw  = (u16*)(ws + 25165824);      // [24M,32M) V compacted fragment images
  u16* Af  = (u16*)(ws + 33554432);      // A images: 24MB (big) or 8MB (small)
  u16* Xw  = (u16*)(ws + 33554432);      // X image (overlaps Af; Af dead by attn)

  // compaction scratch lives in d_out (overwritten by gemm_out at the end)
  int*   inv   = (int*)d_out;                       // 16 KB (compact -> orig)
  float* cbias = (float*)((char*)d_out + 16384);    // 16 KB
  int*   ntb   = (int*)((char*)d_out + 32768);      // 16 B: [0..1]=ntiles, [2..3]=nvalid

  wconv<<<dim3(8, 16, 4), 256, 0, stream>>>(Wq, Wk, Wv, Wo, Wt, WoT);
  maskscan<<<dim3(16, 2), 256, 0, stream>>>(mask, inv, cbias, ntb, Kw, Vw);

  const bool big = (ws_size >= 58720256ull);
  if (big) {
    aconv<<<dim3(16, 32, 3), 256, 0, stream>>>(qry, key, val, Af, inv, ntb, 0, 4194304);
    gemm_qkv_k<<<dim3(768, 1, 1), 512, 0, stream>>>(Af, Wt, Qw, Kw, Vw, ntb, 0, 4194304);
  } else {
    for (int z = 0; z < 3; ++z) {
      aconv<<<dim3(16, 32, 1), 256, 0, stream>>>(qry, key, val, Af, inv, ntb, z, 0);
      gemm_qkv_k<<<dim3(256, 1, 1), 512, 0, stream>>>(Af, Wt, Qw, Kw, Vw, ntb, z, 0);
    }
  }
  attn_k<<<dim3(16, 16, 2), 256, 0, stream>>>(Qw, Kw, Vw, cbias, ntb, Xw);
  gemm_out_k<<<dim3(256, 1, 1), 512, 0, stream>>>(Xw, WoT, bo, out);
}